// Round 14
// baseline (1951.503 us; speedup 1.0000x reference)
//
#include <hip/hip_runtime.h>

#define B_ROWS  2048
#define T_STEPS 112
#define N1 1300
#define N2 340
#define N3 1400

// per-wave index-list region sizes (entries)
#define R1 384
#define R2 96
#define R3 384

// d_ws float offsets
#define OFF_W2T 0          // [1300][340]
#define OFF_W3T 442000     // [340][1400]
#define OFF_W4T 918000     // [1400][4]
#define OFF_BS1 923600     // 1300
#define OFF_BS2 924900     // 340
#define OFF_BS3 925240     // 1400
#define OFF_BS4 926640     // 4
#define WS_FLOATS 926644

__global__ __launch_bounds__(256) void snn_prep(
    const float* __restrict__ W2, const float* __restrict__ W3, const float* __restrict__ W4,
    const float* __restrict__ b1, const float* __restrict__ bias1,
    const float* __restrict__ b2, const float* __restrict__ bias2,
    const float* __restrict__ b3, const float* __restrict__ bias3,
    const float* __restrict__ b4, const float* __restrict__ bias4,
    float* __restrict__ ws)
{
    for (int idx = blockIdx.x * blockDim.x + threadIdx.x; idx < WS_FLOATS;
         idx += gridDim.x * blockDim.x) {
        float v;
        if (idx < OFF_W3T) {                       // W2T[i][k] = W2[k][i]
            int j = idx; int i = j / N2, k = j % N2;
            v = W2[k * N1 + i];
        } else if (idx < OFF_W4T) {                // W3T[i][k] = W3[k][i]
            int j = idx - OFF_W3T; int i = j / N3, k = j % N3;
            v = W3[k * N2 + i];
        } else if (idx < OFF_BS1) {                // W4T[i][k] = W4[k][i]
            int j = idx - OFF_W4T; int i = j / 4, k = j % 4;
            v = W4[k * N3 + i];
        } else if (idx < OFF_BS2) { int j = idx - OFF_BS1; v = b1[j] + bias1[j]; }
        else if (idx < OFF_BS3)   { int j = idx - OFF_BS2; v = b2[j] + bias2[j]; }
        else if (idx < OFF_BS4)   { int j = idx - OFF_BS3; v = b3[j] + bias3[j]; }
        else                      { int j = idx - OFF_BS4; v = b4[j] + bias4[j]; }
        ws[idx] = v;
    }
}

// Packed fp32 add: one VOP3P for two independent per-component chains.
// Numerically identical to the two scalar adds.
__device__ __forceinline__ float2 pk_add(float2 a, float2 b) {
    float2 d;
    asm("v_pk_add_f32 %0, %1, %2" : "=v"(d) : "v"(a), "v"(b));
    return d;
}
__device__ __forceinline__ void pk_acc4(float4& acc, const float4 r) {
    float2 lo = pk_add(make_float2(acc.x, acc.y), make_float2(r.x, r.y));
    float2 hi = pk_add(make_float2(acc.z, acc.w), make_float2(r.z, r.w));
    acc.x = lo.x; acc.y = lo.y; acc.z = hi.x; acc.w = hi.y;
}

// R13 (best: 1944 us) + final two window removals:
//  (1) P4 depth-1 software pipeline (spike j+1's 6 row-vectors issue while
//      spike j accumulates) — same static live count as the old unroll-2;
//  (2) P5 layer-4 gather unroll 4 -> 8.
// Accumulation order is bit-identical to R13 throughout.
__global__ __launch_bounds__(256, 3) void snn_main(
    const float* __restrict__ x,
    const float* __restrict__ W1,
    const float* __restrict__ ws,
    const float* __restrict__ thr4p,
    float* __restrict__ out)
{
    const int b    = blockIdx.x;
    const int tid  = threadIdx.x;
    const int wave = tid >> 6;
    const int lane = tid & 63;

    const float* __restrict__ W2T = ws + OFF_W2T;
    const float* __restrict__ W3T = ws + OFF_W3T;
    const float* __restrict__ W4T = ws + OFF_W4T;
    const float* __restrict__ bs1 = ws + OFF_BS1;
    const float* __restrict__ bs2 = ws + OFF_BS2;
    const float* __restrict__ bs3 = ws + OFF_BS3;
    const float* __restrict__ bs4 = ws + OFF_BS4;

    __shared__ __align__(16) float pw2[4][340];
    __shared__ __align__(16) float pw3[4][1400];
    __shared__ __align__(16) unsigned short lst1[4 * R1];
    __shared__ __align__(16) unsigned short lst2[4 * R2];
    __shared__ __align__(16) unsigned short lst3[4 * R3];
    __shared__ float h4part[4][4];

    // layer-1 chunk ownership: 21 chunks = 6+5+5+5
    const int c1b = (wave == 0) ? 0 : (wave == 1) ? 6 : (wave == 2) ? 11 : 16;
    const int n1  = (wave == 0) ? 6 : 5;

    float mem1[6] = {0.f,0.f,0.f,0.f,0.f,0.f};
    float mem2[2] = {0.f,0.f};
    float mem3[6] = {0.f,0.f,0.f,0.f,0.f,0.f};
    float mem4 = 0.f;
    float cnt  = 0.f;
    const float thr4 = thr4p[0];

    const float4* __restrict__ xv4 = (const float4*)x;
    const float4* __restrict__ W1v = (const float4*)W1;

    // ---- t-invariant setup ----
    int  k1v[6]; bool val1[6]; float bsv1[6];
    float4 w1r[6];
    #pragma unroll
    for (int u = 0; u < 6; ++u) {
        k1v[u] = (c1b + u) * 64 + lane;
        val1[u] = (u < n1) && (k1v[u] < N1);
        bsv1[u] = val1[u] ? bs1[k1v[u]] : 0.f;
        w1r[u]  = val1[u] ? W1v[k1v[u]] : (float4){0.f,0.f,0.f,0.f};  // W1 row preload
    }
    const bool  has2  = (tid < 84);            // owns layer-2 neuron tid+256
    const float bs2v0 = bs2[tid];
    const float bs2v1 = has2 ? bs2[tid + 256] : 0.f;
    float bs3v[6];
    #pragma unroll
    for (int k = 0; k < 5; ++k) bs3v[k] = bs3[tid + 256 * k];
    bs3v[5] = (tid < 120) ? bs3[tid + 1280] : 0.f;
    const float bs4v = bs4[lane & 3];

    // clamped secondary-chunk offsets (inactive lanes load valid garbage,
    // never stored)
    const int so2 = (lane < 21) ? 4 * lane : 80;     // layer-2 cols 256..339
    const int so3 = (lane < 30) ? 4 * lane : 116;    // layer-3 cols 1280..1399

    float4 xv_n = xv4[b * T_STEPS];                  // prefetch x(0)

    for (int t = 0; t < T_STEPS; ++t) {
        const float4 xv = xv_n;
        if (t + 1 < T_STEPS) xv_n = xv4[b * T_STEPS + t + 1];  // lands during this step
        const float x0 = xv.x / 50.0f + 0.001f;
        const float x1 = xv.y / 50.0f + 0.001f;
        const float x2 = xv.z / 50.0f + 0.001f;
        const float x3 = xv.w / 50.0f + 0.001f;

        // ---------- P1: layer 1 (register-resident W1) + LIF + own-wave list ----------
        unsigned cnt1w = 0;
        #pragma unroll
        for (int u = 0; u < 6; ++u) {
            if (u < n1) {
                float h = 0.f;
                if (val1[u]) {
                    h = bsv1[u] + w1r[u].x * x0 + w1r[u].y * x1
                                + w1r[u].z * x2 + w1r[u].w * x3;
                }
                float m = mem1[u];
                const float r = (m > 1.0f) ? 1.0f : 0.0f;
                m = 0.9f * m + h - r;
                mem1[u] = m;
                const bool sp = val1[u] && (m > 1.0f);
                const unsigned long long bal = __ballot(sp);
                if (sp) {
                    const int pos = (int)cnt1w + (int)__popcll(bal & ((1ull << lane) - 1ull));
                    lst1[wave * R1 + pos] = (unsigned short)k1v[u];
                }
                cnt1w += (unsigned)__popcll(bal);
            }
        }

        // ---------- P2: layer-2 gather (own spikes, full rows) ----------
        // depth-1 software pipeline, unroll 4 (R8's proven shape)
        {
            float4 accA = {0.f,0.f,0.f,0.f};
            float4 accB = {0.f,0.f,0.f,0.f};
            const unsigned short* L = lst1 + wave * R1;
            const float* baseA = W2T + 4 * lane;
            const float* baseB = W2T + 256 + so2;
            const int n = (int)cnt1w;
            int j = 0;
            if (n >= 4) {
                ushort4 i0 = *(const ushort4*)(L);
                int o0 = (int)i0.x * N2, o1 = (int)i0.y * N2;
                int o2 = (int)i0.z * N2, o3 = (int)i0.w * N2;
                float4 rA0 = *(const float4*)(baseA + o0);
                float4 rA1 = *(const float4*)(baseA + o1);
                float4 rA2 = *(const float4*)(baseA + o2);
                float4 rA3 = *(const float4*)(baseA + o3);
                float4 rB0 = *(const float4*)(baseB + o0);
                float4 rB1 = *(const float4*)(baseB + o1);
                float4 rB2 = *(const float4*)(baseB + o2);
                float4 rB3 = *(const float4*)(baseB + o3);
                for (j = 4; j + 4 <= n; j += 4) {
                    ushort4 i1 = *(const ushort4*)(L + j);
                    const int p0 = (int)i1.x * N2, p1 = (int)i1.y * N2;
                    const int p2 = (int)i1.z * N2, p3 = (int)i1.w * N2;
                    float4 sA0 = *(const float4*)(baseA + p0);
                    float4 sA1 = *(const float4*)(baseA + p1);
                    float4 sA2 = *(const float4*)(baseA + p2);
                    float4 sA3 = *(const float4*)(baseA + p3);
                    float4 sB0 = *(const float4*)(baseB + p0);
                    float4 sB1 = *(const float4*)(baseB + p1);
                    float4 sB2 = *(const float4*)(baseB + p2);
                    float4 sB3 = *(const float4*)(baseB + p3);
                    pk_acc4(accA, rA0); pk_acc4(accB, rB0);
                    pk_acc4(accA, rA1); pk_acc4(accB, rB1);
                    pk_acc4(accA, rA2); pk_acc4(accB, rB2);
                    pk_acc4(accA, rA3); pk_acc4(accB, rB3);
                    rA0 = sA0; rA1 = sA1; rA2 = sA2; rA3 = sA3;
                    rB0 = sB0; rB1 = sB1; rB2 = sB2; rB3 = sB3;
                }
                pk_acc4(accA, rA0); pk_acc4(accB, rB0);
                pk_acc4(accA, rA1); pk_acc4(accB, rB1);
                pk_acc4(accA, rA2); pk_acc4(accB, rB2);
                pk_acc4(accA, rA3); pk_acc4(accB, rB3);
            }
            for (; j < n; ++j) {
                const int o = (int)L[j] * N2;
                float4 rA = *(const float4*)(baseA + o);
                float4 rB = *(const float4*)(baseB + o);
                pk_acc4(accA, rA); pk_acc4(accB, rB);
            }
            *(float4*)&pw2[wave][4 * lane] = accA;
            if (lane < 21) *(float4*)&pw2[wave][256 + 4 * lane] = accB;
        }
        __syncthreads();  // B1: pw2 ready (also fences h4part of t-1)

        // ---------- deferred layer-4 combine for step t-1 (wave 3) ----------
        if (wave == 3 && t > 0) {
            float h4 = bs4v + h4part[0][lane & 3];
            h4 += h4part[1][lane & 3];
            h4 += h4part[2][lane & 3];
            h4 += h4part[3][lane & 3];
            float m4 = mem4;
            const float r4 = (m4 > thr4) ? thr4 : 0.f;
            m4 = 0.9f * m4 + h4 - r4;
            mem4 = m4;
            const float s4 = (m4 > thr4) ? 1.f : 0.f;
            if (lane < 4) {
                out[8192 + (b * T_STEPS + (t - 1)) * 4 + lane] = s4;
                cnt += s4;
            }
        }

        // ---------- P3: LIF-2 (thread-linear) + own-wave list ----------
        unsigned cnt2w = 0;
        {
            const float h0 = pw2[0][tid] + pw2[1][tid] + pw2[2][tid] + pw2[3][tid] + bs2v0;
            float m = mem2[0];
            const float r = (m > 1.0f) ? 1.0f : 0.0f;
            m = 0.9f * m + h0 - r;
            mem2[0] = m;
            const bool sp0 = (m > 1.0f);
            const unsigned long long bal0 = __ballot(sp0);
            if (sp0) {
                const int pos = (int)__popcll(bal0 & ((1ull << lane) - 1ull));
                lst2[wave * R2 + pos] = (unsigned short)tid;
            }
            cnt2w += (unsigned)__popcll(bal0);

            float h1 = 0.f;
            if (has2) h1 = pw2[0][tid+256] + pw2[1][tid+256] + pw2[2][tid+256] + pw2[3][tid+256] + bs2v1;
            float m1v = mem2[1];
            const float r1v = (m1v > 1.0f) ? 1.0f : 0.0f;
            m1v = 0.9f * m1v + h1 - r1v;
            mem2[1] = m1v;
            const bool sp1 = has2 && (m1v > 1.0f);
            const unsigned long long bal1 = __ballot(sp1);
            if (sp1) {
                const int pos = (int)cnt2w + (int)__popcll(bal1 & ((1ull << lane) - 1ull));
                lst2[wave * R2 + pos] = (unsigned short)(tid + 256);
            }
            cnt2w += (unsigned)__popcll(bal1);
        }

        // ---------- P4: layer-3 gather (own spikes, full rows) ----------
        // depth-1 software pipeline: spike j+1's 6 row-vectors issue while
        // spike j accumulates. Ascending-j order preserved (bit-identical).
        {
            float4 acc3[6];
            #pragma unroll
            for (int c = 0; c < 6; ++c) acc3[c] = (float4){0.f,0.f,0.f,0.f};
            const unsigned short* L = lst2 + wave * R2;
            const int n = (int)cnt2w;
            if (n >= 1) {
                const float* ra = W3T + (int)L[0] * N3;
                float4 r0 = *(const float4*)(ra + 4*lane);
                float4 r1 = *(const float4*)(ra + 256 + 4*lane);
                float4 r2 = *(const float4*)(ra + 512 + 4*lane);
                float4 r3 = *(const float4*)(ra + 768 + 4*lane);
                float4 r4 = *(const float4*)(ra + 1024 + 4*lane);
                float4 r5 = *(const float4*)(ra + 1280 + so3);
                for (int j = 1; j < n; ++j) {
                    const float* rb = W3T + (int)L[j] * N3;
                    float4 s0 = *(const float4*)(rb + 4*lane);
                    float4 s1 = *(const float4*)(rb + 256 + 4*lane);
                    float4 s2 = *(const float4*)(rb + 512 + 4*lane);
                    float4 s3 = *(const float4*)(rb + 768 + 4*lane);
                    float4 s4 = *(const float4*)(rb + 1024 + 4*lane);
                    float4 s5 = *(const float4*)(rb + 1280 + so3);
                    pk_acc4(acc3[0], r0); pk_acc4(acc3[1], r1); pk_acc4(acc3[2], r2);
                    pk_acc4(acc3[3], r3); pk_acc4(acc3[4], r4); pk_acc4(acc3[5], r5);
                    r0 = s0; r1 = s1; r2 = s2; r3 = s3; r4 = s4; r5 = s5;
                }
                pk_acc4(acc3[0], r0); pk_acc4(acc3[1], r1); pk_acc4(acc3[2], r2);
                pk_acc4(acc3[3], r3); pk_acc4(acc3[4], r4); pk_acc4(acc3[5], r5);
            }
            #pragma unroll
            for (int c = 0; c < 5; ++c)
                *(float4*)&pw3[wave][c * 256 + 4 * lane] = acc3[c];
            if (lane < 30) *(float4*)&pw3[wave][1280 + 4 * lane] = acc3[5];
        }
        __syncthreads();  // B2: pw3 ready

        // ---------- P5: LIF-3 + own list + layer-4 partial gather (unroll 8) ----------
        {
            unsigned cnt3w = 0;
            #pragma unroll
            for (int k = 0; k < 6; ++k) {
                const bool valid = (k < 5) || (tid < 120);
                const int n = tid + 256 * k;
                float h = 0.f;
                if (valid) h = pw3[0][n] + pw3[1][n] + pw3[2][n] + pw3[3][n] + bs3v[k];
                float m = mem3[k];
                const float r = (m > 1.0f) ? 1.0f : 0.0f;
                m = 0.9f * m + h - r;
                mem3[k] = m;
                const bool sp = valid && (m > 1.0f);
                const unsigned long long bal = __ballot(sp);
                if (sp) {
                    const int pos = (int)cnt3w + (int)__popcll(bal & ((1ull << lane) - 1ull));
                    lst3[wave * R3 + pos] = (unsigned short)n;
                }
                cnt3w += (unsigned)__popcll(bal);
            }
            // layer-4 partials from own spikes (wave-local), unroll 8
            float h4p = 0.f;
            const unsigned short* L = lst3 + wave * R3;
            const int o4 = lane & 3;
            int j = 0;
            for (; j + 8 <= (int)cnt3w; j += 8) {
                ushort4 ia = *(const ushort4*)(L + j);
                ushort4 ib = *(const ushort4*)(L + j + 4);
                float t0 = W4T[4 * (int)ia.x + o4];
                float t1 = W4T[4 * (int)ia.y + o4];
                float t2 = W4T[4 * (int)ia.z + o4];
                float t3 = W4T[4 * (int)ia.w + o4];
                float t4 = W4T[4 * (int)ib.x + o4];
                float t5 = W4T[4 * (int)ib.y + o4];
                float t6 = W4T[4 * (int)ib.z + o4];
                float t7 = W4T[4 * (int)ib.w + o4];
                h4p += t0; h4p += t1; h4p += t2; h4p += t3;
                h4p += t4; h4p += t5; h4p += t6; h4p += t7;
            }
            for (; j + 4 <= (int)cnt3w; j += 4) {
                ushort4 ii = *(const ushort4*)(L + j);
                float t0 = W4T[4 * (int)ii.x + o4];
                float t1 = W4T[4 * (int)ii.y + o4];
                float t2 = W4T[4 * (int)ii.z + o4];
                float t3 = W4T[4 * (int)ii.w + o4];
                h4p += t0; h4p += t1; h4p += t2; h4p += t3;
            }
            for (; j < (int)cnt3w; ++j) h4p += W4T[4 * (int)L[j] + o4];
            if (lane < 4) h4part[wave][lane] = h4p;
        }
        // no barrier: next fence is B1 of t+1, which publishes h4part to wave 3
    }

    __syncthreads();  // fence h4part of final step
    if (wave == 3) {
        float h4 = bs4v + h4part[0][lane & 3];
        h4 += h4part[1][lane & 3];
        h4 += h4part[2][lane & 3];
        h4 += h4part[3][lane & 3];
        float m4 = mem4;
        const float r4 = (m4 > thr4) ? thr4 : 0.f;
        m4 = 0.9f * m4 + h4 - r4;
        const float s4 = (m4 > thr4) ? 1.f : 0.f;
        if (lane < 4) {
            out[8192 + (b * T_STEPS + (T_STEPS - 1)) * 4 + lane] = s4;
            cnt += s4;
            out[b * 4 + lane] = cnt;
        }
    }
}

extern "C" void kernel_launch(void* const* d_in, const int* in_sizes, int n_in,
                              void* d_out, int out_size, void* d_ws, size_t ws_size,
                              hipStream_t stream)
{
    const float* x     = (const float*)d_in[0];
    const float* W1    = (const float*)d_in[1];
    const float* b1    = (const float*)d_in[2];
    const float* bias1 = (const float*)d_in[3];
    const float* W2    = (const float*)d_in[4];
    const float* b2    = (const float*)d_in[5];
    const float* bias2 = (const float*)d_in[6];
    const float* W3    = (const float*)d_in[7];
    const float* b3    = (const float*)d_in[8];
    const float* bias3 = (const float*)d_in[9];
    const float* W4    = (const float*)d_in[10];
    const float* b4    = (const float*)d_in[11];
    const float* bias4 = (const float*)d_in[12];
    const float* thr4  = (const float*)d_in[13];
    float* out = (float*)d_out;
    float* ws  = (float*)d_ws;

    hipLaunchKernelGGL(snn_prep, dim3(1024), dim3(256), 0, stream,
                       W2, W3, W4, b1, bias1, b2, bias2, b3, bias3, b4, bias4, ws);
    hipLaunchKernelGGL(snn_main, dim3(B_ROWS), dim3(256), 0, stream,
                       x, W1, ws, thr4, out);
}